// Round 3
// baseline (163.435 us; speedup 1.0000x reference)
//
#include <hip/hip_runtime.h>

typedef unsigned short u16;
typedef unsigned int u32;

#define NB 2048       // B
#define NMC 4         // MC
#define NU 20000      // U
#define ND 128        // DIN = DOUT
#define EPB 32        // edges per row = E/B

// ---------------------------------------------------------------------------
// Gathered GEMM, f32 in / f32 out: out[r] = table[ids[r]] @ W
// Block = 256 threads, tile 128 rows x 128 cols, K processed in 2 halves of 64
// (keeps static LDS at 64 KB). Per-thread 8x8 register tile.
// Grid: blocks [0,157): embed_v (M=20000)
//       blocks [157,253): 6 products of M=2048 (16 blocks each)
// ---------------------------------------------------------------------------
#define GEMM_BR 128
#define EMBED_BLOCKS 157   // ceil(20000/128)

__global__ __launch_bounds__(256) void gemm_all(
    const float* __restrict__ agg, const float* __restrict__ ff,
    const float* __restrict__ Wv_agg, const float* __restrict__ Wv_ff,
    const float* __restrict__ Wk, const float* __restrict__ Wq,
    const int* __restrict__ uids, const int* __restrict__ nodes,
    float* __restrict__ embed_v,
    float* __restrict__ selfA, float* __restrict__ selfF,
    float* __restrict__ K0, float* __restrict__ K1,
    float* __restrict__ Q0, float* __restrict__ Q1)
{
    __shared__ float Ws[64 * ND];   // W[k][c] for current k-half (32 KB)
    __shared__ float As[64 * ND];   // A^T[k][r] for current k-half (32 KB)

    const int bx = blockIdx.x;
    const int t  = threadIdx.x;

    const float* table = agg; const int* ids = uids; const float* W = Wv_agg;
    float* outp = embed_v;
    int M, r0;
    if (bx < EMBED_BLOCKS) {
        M = NU; r0 = bx * GEMM_BR;
    } else {
        int z = bx - EMBED_BLOCKS;
        int mode = z >> 4;               // 0..5
        r0 = (z & 15) * GEMM_BR;
        M = NB; ids = nodes;
        switch (mode) {
            case 0: table = agg; W = Wv_agg; outp = selfA; break;
            case 1: table = agg; W = Wk;     outp = K0;    break;
            case 2: table = agg; W = Wq;     outp = Q0;    break;
            case 3: table = ff;  W = Wv_ff;  outp = selfF; break;
            case 4: table = ff;  W = Wk;     outp = K1;    break;
            default: table = ff; W = Wq;     outp = Q1;    break;
        }
    }

    // gather id once (row this thread stages)
    const int rs = t >> 1;          // 0..127 (staging row)
    const int hs = t & 1;           // k sub-half (32 floats)
    int srow = r0 + rs;
    const int id = ids[srow < M ? srow : (M - 1)];

    const int rt = (t >> 4) * 8;    // 0..120
    const int ct = (t & 15) * 8;    // 0..120

    float acc[8][8];
    #pragma unroll
    for (int i = 0; i < 8; i++)
        #pragma unroll
        for (int j = 0; j < 8; j++) acc[i][j] = 0.f;

    for (int kk = 0; kk < ND; kk += 64) {
        // stage W half: 64x128 f32 = 2048 float4, 8 per thread
        {
            const float4* src = (const float4*)(W + kk * ND);
            float4* dst = (float4*)Ws;
            #pragma unroll
            for (int i = 0; i < 8; i++) dst[t + i * 256] = src[t + i * 256];
        }
        // stage A half transposed: thread stages 32 floats of its row
        {
            const float4* src = (const float4*)(table + (size_t)id * ND + kk + hs * 32);
            #pragma unroll
            for (int i = 0; i < 8; i++) {
                float4 v = src[i];
                int k = hs * 32 + i * 4;
                As[(k + 0) * GEMM_BR + rs] = v.x;
                As[(k + 1) * GEMM_BR + rs] = v.y;
                As[(k + 2) * GEMM_BR + rs] = v.z;
                As[(k + 3) * GEMM_BR + rs] = v.w;
            }
        }
        __syncthreads();

        #pragma unroll 2
        for (int k = 0; k < 64; k++) {
            float4 a0 = *(const float4*)&As[k * GEMM_BR + rt];
            float4 a1 = *(const float4*)&As[k * GEMM_BR + rt + 4];
            float4 w0 = *(const float4*)&Ws[k * ND + ct];
            float4 w1 = *(const float4*)&Ws[k * ND + ct + 4];
            float a[8] = {a0.x, a0.y, a0.z, a0.w, a1.x, a1.y, a1.z, a1.w};
            float w[8] = {w0.x, w0.y, w0.z, w0.w, w1.x, w1.y, w1.z, w1.w};
            #pragma unroll
            for (int i = 0; i < 8; i++)
                #pragma unroll
                for (int j = 0; j < 8; j++) acc[i][j] += a[i] * w[j];
        }
        __syncthreads();
    }

    #pragma unroll
    for (int i = 0; i < 8; i++) {
        int row = r0 + rt + i;
        if (row >= M) continue;
        float4* o = (float4*)&outp[(size_t)row * ND + ct];
        o[0] = make_float4(acc[i][0], acc[i][1], acc[i][2], acc[i][3]);
        o[1] = make_float4(acc[i][4], acc[i][5], acc[i][6], acc[i][7]);
    }
}

// ---------------------------------------------------------------------------
// Per-row finalize: dedupe edges, neigh averages, persona softmax,
// 2x2 highway attention, ELU, f32 output. 1 block (128 thr) per row b.
// ---------------------------------------------------------------------------
__global__ __launch_bounds__(128) void finalize(
    const int* __restrict__ layer_idx, const int* __restrict__ col_idx,
    const float* __restrict__ embed_v,
    const float* __restrict__ selfA, const float* __restrict__ selfF,
    const float* __restrict__ K0, const float* __restrict__ K1,
    const float* __restrict__ Q0, const float* __restrict__ Q1,
    const float* __restrict__ mu_w, float* __restrict__ out)
{
    const int b = blockIdx.x;
    const int t = threadIdx.x;          // 0..127

    __shared__ int   Ls[EPB], Cs[EPB], cnt[NMC];
    __shared__ float keepf[EPB];
    __shared__ float red[14 * 2];
    __shared__ float bc[8];

    if (t < NMC) cnt[t] = 0;
    if (t < EPB) {
        Ls[t] = layer_idx[b * EPB + t];
        Cs[t] = col_idx[b * EPB + t];
    }
    __syncthreads();
    if (t < EPB) {
        int l = Ls[t], c = Cs[t];
        int kp = 1;
        for (int j = 0; j < t; j++)
            if (Ls[j] == l && Cs[j] == c) { kp = 0; break; }
        keepf[t] = kp ? 1.0f : 0.0f;
        if (kp) atomicAdd(&cnt[l], 1);
    }
    __syncthreads();

    // accumulate neigh sums per layer (exact set semantics via keepf)
    float a0 = 0.f, a1 = 0.f, a2 = 0.f, a3 = 0.f;
    #pragma unroll
    for (int e = 0; e < EPB; e++) {
        float v = embed_v[(size_t)Cs[e] * ND + t];
        float vk = v * keepf[e];
        int l = Ls[e];
        a0 += (l == 0) ? vk : 0.f;
        a1 += (l == 1) ? vk : 0.f;
        a2 += (l == 2) ? vk : 0.f;
        a3 += (l == 3) ? vk : 0.f;
    }
    float inv0 = cnt[0] > 0 ? 1.f / (float)cnt[0] : 0.f;
    float inv1 = cnt[1] > 0 ? 1.f / (float)cnt[1] : 0.f;
    float inv2 = cnt[2] > 0 ? 1.f / (float)cnt[2] : 0.f;
    float inv3 = cnt[3] > 0 ? 1.f / (float)cnt[3] : 0.f;
    float n0 = a0 * inv0, n1 = a1 * inv1, n2 = a2 * inv2, n3 = a3 * inv3;

    const size_t base = (size_t)b * ND + t;
    float sA = selfA[base];
    float sF = selfF[base];
    float k0 = K0[base], k1 = K1[base], q0 = Q0[base], q1 = Q1[base];
    float mu0 = mu_w[t], mu1 = mu_w[ND + t];

    float vals[14] = {
        sA * sA, sA * mu0,
        n0 * n0, n1 * n1, n2 * n2, n3 * n3,
        n0 * mu1, n1 * mu1, n2 * mu1, n3 * mu1,
        k0 * q0, k0 * q1, k1 * q0, k1 * q1
    };
    const int lane = t & 63, wv = t >> 6;
    #pragma unroll
    for (int s = 0; s < 14; s++) {
        float v = vals[s];
        #pragma unroll
        for (int off = 32; off; off >>= 1) v += __shfl_xor(v, off);
        if (lane == 0) red[s * 2 + wv] = v;
    }
    __syncthreads();

    if (t == 0) {
        float sn = red[0] + red[1];          // ||selfA||^2
        float ds = red[2] + red[3];          // selfA . mu0
        float sc[NMC], mx = -1e30f;
        #pragma unroll
        for (int m = 0; m < NMC; m++) {
            float nn = red[(2 + m) * 2] + red[(2 + m) * 2 + 1];
            float dn = red[(6 + m) * 2] + red[(6 + m) * 2 + 1];
            float nrm = fmaxf(sqrtf(sn + nn), 1e-12f);
            sc[m] = (ds + dn) / nrm;
            mx = fmaxf(mx, sc[m]);
        }
        float se = 0.f, ee[NMC];
        #pragma unroll
        for (int m = 0; m < NMC; m++) { ee[m] = expf(sc[m] - mx); se += ee[m]; }
        #pragma unroll
        for (int m = 0; m < NMC; m++) bc[m] = ee[m] / se;

        float s00 = (red[20] + red[21]) * (1.f / 128.f);
        float s01 = (red[22] + red[23]) * (1.f / 128.f);
        float s10 = (red[24] + red[25]) * (1.f / 128.f);
        float s11 = (red[26] + red[27]) * (1.f / 128.f);
        float m0 = fmaxf(s00, s01), e00 = expf(s00 - m0), e01 = expf(s01 - m0);
        float d0 = e00 + e01;
        bc[4] = e00 / d0; bc[5] = e01 / d0;
        float m1 = fmaxf(s10, s11), e10 = expf(s10 - m1), e11 = expf(s11 - m1);
        float d1 = e10 + e11;
        bc[6] = e10 / d1; bc[7] = e11 / d1;
    }
    __syncthreads();

    float nsum = n0 * bc[0] + n1 * bc[1] + n2 * bc[2] + n3 * bc[3];
    float sa1 = (sA + nsum) * 0.5f;
    float new0 = bc[4] * sa1 + bc[5] * sF;
    float new1 = bc[6] * sa1 + bc[7] * sF;
    float o0 = 0.9f * sa1 + 0.1f * new0;
    float o1 = 0.9f * sF  + 0.1f * new1;
    o0 = o0 > 0.f ? o0 : (expf(o0) - 1.f);
    o1 = o1 > 0.f ? o1 : (expf(o1) - 1.f);
    out[base] = o0;
    out[(size_t)NB * ND + base] = o1;
}

// ---------------------------------------------------------------------------
extern "C" void kernel_launch(void* const* d_in, const int* in_sizes, int n_in,
                              void* d_out, int out_size, void* d_ws, size_t ws_size,
                              hipStream_t stream) {
    const int* nodes  = (const int*)d_in[0];
    const int* uids   = (const int*)d_in[1];
    // d_in[2] row_idx: deterministic repeat(arange(B), 32) — used implicitly
    const int* layer  = (const int*)d_in[3];
    const int* col    = (const int*)d_in[4];
    const float* agg    = (const float*)d_in[5];
    const float* ff     = (const float*)d_in[6];
    const float* Wv_agg = (const float*)d_in[7];
    const float* Wv_ff  = (const float*)d_in[8];
    const float* Wk     = (const float*)d_in[9];
    const float* Wq     = (const float*)d_in[10];
    const float* mu     = (const float*)d_in[11];

    // workspace layout (all f32): embed_v then 6 B-side products (~15.8 MiB)
    float* embed_v = (float*)d_ws;                      // 20000*128 = 10.24 MB
    float* selfA   = embed_v + (size_t)NU * ND;
    float* selfF   = selfA + (size_t)NB * ND;
    float* K0      = selfF + (size_t)NB * ND;
    float* K1      = K0 + (size_t)NB * ND;
    float* Q0      = K1 + (size_t)NB * ND;
    float* Q1      = Q0 + (size_t)NB * ND;

    float* out = (float*)d_out;

    gemm_all<<<EMBED_BLOCKS + 6 * (NB / GEMM_BR), 256, 0, stream>>>(
        agg, ff, Wv_agg, Wv_ff, Wk, Wq, uids, nodes,
        embed_v, selfA, selfF, K0, K1, Q0, Q1);

    finalize<<<NB, 128, 0, stream>>>(
        layer, col, embed_v, selfA, selfF, K0, K1, Q0, Q1, mu, out);
}

// Round 4
// 152.585 us; speedup vs baseline: 1.0711x; 1.0711x over previous
//
#include <hip/hip_runtime.h>
#include <hip/hip_bf16.h>

typedef unsigned short u16;
typedef unsigned int u32;

#define NB 2048       // B
#define NMC 4         // MC
#define NU 20000      // U
#define ND 128        // DIN = DOUT
#define EPB 32        // edges per row = E/B

typedef __attribute__((ext_vector_type(8))) short bf16x8;
typedef __attribute__((ext_vector_type(4))) float f32x4;

__device__ __forceinline__ u32 pack_bf16(float a, float b) {
    __hip_bfloat162 h = __float22bfloat162_rn(make_float2(a, b));
    return *(u32*)&h;
}

// ---------------------------------------------------------------------------
// Prep: WT[mat][c][k] bf16  <-  W[k][c] f32, for {Wv_agg, Wk, Wq, Wv_ff}.
// 32 blocks x 256 thr; block = (matrix, 16-row k-slice).
// ---------------------------------------------------------------------------
__global__ __launch_bounds__(256) void prep_wt(
    const float* __restrict__ Wv_agg, const float* __restrict__ Wk,
    const float* __restrict__ Wq, const float* __restrict__ Wv_ff,
    u16* __restrict__ WT)
{
    __shared__ float Wl[16 * ND];
    const int m = blockIdx.x >> 3;
    const int ks = (blockIdx.x & 7) * 16;
    const int t = threadIdx.x;

    const float* W = (m == 0) ? Wv_agg : (m == 1) ? Wk : (m == 2) ? Wq : Wv_ff;
    // coalesced load of 16x128 slice
    const float4* src = (const float4*)(W + ks * ND);
    float4* dst = (float4*)Wl;
    dst[t * 2] = src[t * 2];
    dst[t * 2 + 1] = src[t * 2 + 1];
    __syncthreads();

    const int c = t >> 1, kh = t & 1;
    float v[8];
    #pragma unroll
    for (int j = 0; j < 8; j++) v[j] = Wl[(kh * 8 + j) * ND + c];
    uint4 pk;
    pk.x = pack_bf16(v[0], v[1]);
    pk.y = pack_bf16(v[2], v[3]);
    pk.z = pack_bf16(v[4], v[5]);
    pk.w = pack_bf16(v[6], v[7]);
    *(uint4*)&WT[((size_t)(m * ND + c)) * ND + ks + kh * 8] = pk;
}

// ---------------------------------------------------------------------------
// Gathered GEMM via bf16 MFMA: out[r] = table[ids[r]] @ W
// Block 256 thr = 4 waves; tile 128x128; K in 2 passes of 64 (LDS 2x9 KB... 
// stride 72 bf16 = 64 data + 8 pad, conflict-free b128).
// Wave w: rows [32w,32w+32) = 2 row-tiles x 8 col-tiles of 16x16x32 MFMA.
// Grid: [0,157) embed_v; [157,253) six M=2048 products (16 blocks each).
// ---------------------------------------------------------------------------
#define LDSK 72
#define EMBED_BLOCKS 157

__global__ __launch_bounds__(256) void gemm_all(
    const float* __restrict__ agg, const float* __restrict__ ff,
    const u16* __restrict__ WT,
    const int* __restrict__ uids, const int* __restrict__ nodes,
    float* __restrict__ embed_v,
    float* __restrict__ selfA, float* __restrict__ selfF,
    float* __restrict__ K0, float* __restrict__ K1,
    float* __restrict__ Q0, float* __restrict__ Q1)
{
    __shared__ u16 As[ND * LDSK];
    __shared__ u16 Bs[ND * LDSK];

    const int bx = blockIdx.x;
    const int t  = threadIdx.x;

    const float* table = agg; const int* ids = uids; int wtm = 0;
    float* outp = embed_v;
    int M, r0;
    if (bx < EMBED_BLOCKS) {
        M = NU; r0 = bx * 128;
    } else {
        int z = bx - EMBED_BLOCKS;
        int mode = z >> 4;
        r0 = (z & 15) * 128;
        M = NB; ids = nodes;
        switch (mode) {
            case 0: table = agg; wtm = 0; outp = selfA; break;
            case 1: table = agg; wtm = 1; outp = K0;    break;
            case 2: table = agg; wtm = 2; outp = Q0;    break;
            case 3: table = ff;  wtm = 3; outp = selfF; break;
            case 4: table = ff;  wtm = 1; outp = K1;    break;
            default: table = ff; wtm = 2; outp = Q1;    break;
        }
    }

    const int rs = t >> 1, hs = t & 1;     // staging row/col 0..127, k-half
    int srow = r0 + rs;
    const int id = ids[srow < M ? srow : (M - 1)];
    const float* arow = table + (size_t)id * ND;
    const u16* wrow = WT + ((size_t)(wtm * ND + rs)) * ND;

    const int w = t >> 6, lane = t & 63, q = lane >> 4, li = lane & 15;

    f32x4 acc[2][8];
    #pragma unroll
    for (int i = 0; i < 2; i++)
        #pragma unroll
        for (int j = 0; j < 8; j++) acc[i][j] = (f32x4){0.f, 0.f, 0.f, 0.f};

    for (int pass = 0; pass < 2; pass++) {
        const int k0 = pass * 64;
        // stage A: load 32 f32 of gathered row, convert, write 4x b128
        {
            const float4* asrc = (const float4*)(arow + k0 + hs * 32);
            #pragma unroll
            for (int i = 0; i < 4; i++) {
                float4 v0 = asrc[2 * i], v1 = asrc[2 * i + 1];
                uint4 pk;
                pk.x = pack_bf16(v0.x, v0.y);
                pk.y = pack_bf16(v0.z, v0.w);
                pk.z = pack_bf16(v1.x, v1.y);
                pk.w = pack_bf16(v1.z, v1.w);
                *(uint4*)&As[rs * LDSK + hs * 32 + i * 8] = pk;
            }
        }
        // stage B (already bf16, pre-transposed): 4x 16B copies
        {
            const uint4* bsrc = (const uint4*)(wrow + k0 + hs * 32);
            #pragma unroll
            for (int i = 0; i < 4; i++)
                *(uint4*)&Bs[rs * LDSK + hs * 32 + i * 8] = bsrc[i];
        }
        __syncthreads();

        #pragma unroll
        for (int c = 0; c < 2; c++) {
            const int kk = c * 32 + q * 8;
            bf16x8 af[2], bfr[8];
            #pragma unroll
            for (int tr = 0; tr < 2; tr++)
                af[tr] = *(const bf16x8*)&As[(w * 32 + tr * 16 + li) * LDSK + kk];
            #pragma unroll
            for (int tc = 0; tc < 8; tc++)
                bfr[tc] = *(const bf16x8*)&Bs[(tc * 16 + li) * LDSK + kk];
            #pragma unroll
            for (int tr = 0; tr < 2; tr++)
                #pragma unroll
                for (int tc = 0; tc < 8; tc++)
                    acc[tr][tc] = __builtin_amdgcn_mfma_f32_16x16x32_bf16(
                        af[tr], bfr[tc], acc[tr][tc], 0, 0, 0);
        }
        __syncthreads();
    }

    // epilogue: C/D layout col=lane&15, row=quad*4+reg
    #pragma unroll
    for (int tr = 0; tr < 2; tr++) {
        const int rloc = w * 32 + tr * 16 + q * 4;
        #pragma unroll
        for (int r = 0; r < 4; r++) {
            const int row = r0 + rloc + r;
            if (row < M) {
                #pragma unroll
                for (int tc = 0; tc < 8; tc++)
                    outp[(size_t)row * ND + tc * 16 + li] = acc[tr][tc][r];
            }
        }
    }
}

// ---------------------------------------------------------------------------
// Per-row finalize: dedupe edges, neigh averages, persona softmax,
// 2x2 highway attention, ELU, f32 output. 1 block (128 thr) per row b.
// ---------------------------------------------------------------------------
__global__ __launch_bounds__(128) void finalize(
    const int* __restrict__ layer_idx, const int* __restrict__ col_idx,
    const float* __restrict__ embed_v,
    const float* __restrict__ selfA, const float* __restrict__ selfF,
    const float* __restrict__ K0, const float* __restrict__ K1,
    const float* __restrict__ Q0, const float* __restrict__ Q1,
    const float* __restrict__ mu_w, float* __restrict__ out)
{
    const int b = blockIdx.x;
    const int t = threadIdx.x;          // 0..127

    __shared__ int   Ls[EPB], Cs[EPB], cnt[NMC];
    __shared__ float keepf[EPB];
    __shared__ float red[14 * 2];
    __shared__ float bc[8];

    if (t < NMC) cnt[t] = 0;
    if (t < EPB) {
        Ls[t] = layer_idx[b * EPB + t];
        Cs[t] = col_idx[b * EPB + t];
    }
    __syncthreads();
    if (t < EPB) {
        int l = Ls[t], c = Cs[t];
        int kp = 1;
        for (int j = 0; j < t; j++)
            if (Ls[j] == l && Cs[j] == c) { kp = 0; break; }
        keepf[t] = kp ? 1.0f : 0.0f;
        if (kp) atomicAdd(&cnt[l], 1);
    }
    __syncthreads();

    float a0 = 0.f, a1 = 0.f, a2 = 0.f, a3 = 0.f;
    #pragma unroll
    for (int e = 0; e < EPB; e++) {
        float v = embed_v[(size_t)Cs[e] * ND + t];
        float vk = v * keepf[e];
        int l = Ls[e];
        a0 += (l == 0) ? vk : 0.f;
        a1 += (l == 1) ? vk : 0.f;
        a2 += (l == 2) ? vk : 0.f;
        a3 += (l == 3) ? vk : 0.f;
    }
    float inv0 = cnt[0] > 0 ? 1.f / (float)cnt[0] : 0.f;
    float inv1 = cnt[1] > 0 ? 1.f / (float)cnt[1] : 0.f;
    float inv2 = cnt[2] > 0 ? 1.f / (float)cnt[2] : 0.f;
    float inv3 = cnt[3] > 0 ? 1.f / (float)cnt[3] : 0.f;
    float n0 = a0 * inv0, n1 = a1 * inv1, n2 = a2 * inv2, n3 = a3 * inv3;

    const size_t base = (size_t)b * ND + t;
    float sA = selfA[base];
    float sF = selfF[base];
    float k0 = K0[base], k1 = K1[base], q0 = Q0[base], q1 = Q1[base];
    float mu0 = mu_w[t], mu1 = mu_w[ND + t];

    float vals[14] = {
        sA * sA, sA * mu0,
        n0 * n0, n1 * n1, n2 * n2, n3 * n3,
        n0 * mu1, n1 * mu1, n2 * mu1, n3 * mu1,
        k0 * q0, k0 * q1, k1 * q0, k1 * q1
    };
    const int lane = t & 63, wv = t >> 6;
    #pragma unroll
    for (int s = 0; s < 14; s++) {
        float v = vals[s];
        #pragma unroll
        for (int off = 32; off; off >>= 1) v += __shfl_xor(v, off);
        if (lane == 0) red[s * 2 + wv] = v;
    }
    __syncthreads();

    if (t == 0) {
        float sn = red[0] + red[1];          // ||selfA||^2
        float ds = red[2] + red[3];          // selfA . mu0
        float sc[NMC], mx = -1e30f;
        #pragma unroll
        for (int m = 0; m < NMC; m++) {
            float nn = red[(2 + m) * 2] + red[(2 + m) * 2 + 1];
            float dn = red[(6 + m) * 2] + red[(6 + m) * 2 + 1];
            float nrm = fmaxf(sqrtf(sn + nn), 1e-12f);
            sc[m] = (ds + dn) / nrm;
            mx = fmaxf(mx, sc[m]);
        }
        float se = 0.f, ee[NMC];
        #pragma unroll
        for (int m = 0; m < NMC; m++) { ee[m] = expf(sc[m] - mx); se += ee[m]; }
        #pragma unroll
        for (int m = 0; m < NMC; m++) bc[m] = ee[m] / se;

        float s00 = (red[20] + red[21]) * (1.f / 128.f);
        float s01 = (red[22] + red[23]) * (1.f / 128.f);
        float s10 = (red[24] + red[25]) * (1.f / 128.f);
        float s11 = (red[26] + red[27]) * (1.f / 128.f);
        float m0 = fmaxf(s00, s01), e00 = expf(s00 - m0), e01 = expf(s01 - m0);
        float d0 = e00 + e01;
        bc[4] = e00 / d0; bc[5] = e01 / d0;
        float m1 = fmaxf(s10, s11), e10 = expf(s10 - m1), e11 = expf(s11 - m1);
        float d1 = e10 + e11;
        bc[6] = e10 / d1; bc[7] = e11 / d1;
    }
    __syncthreads();

    float nsum = n0 * bc[0] + n1 * bc[1] + n2 * bc[2] + n3 * bc[3];
    float sa1 = (sA + nsum) * 0.5f;
    float new0 = bc[4] * sa1 + bc[5] * sF;
    float new1 = bc[6] * sa1 + bc[7] * sF;
    float o0 = 0.9f * sa1 + 0.1f * new0;
    float o1 = 0.9f * sF  + 0.1f * new1;
    o0 = o0 > 0.f ? o0 : (expf(o0) - 1.f);
    o1 = o1 > 0.f ? o1 : (expf(o1) - 1.f);
    out[base] = o0;
    out[(size_t)NB * ND + base] = o1;
}

// ---------------------------------------------------------------------------
extern "C" void kernel_launch(void* const* d_in, const int* in_sizes, int n_in,
                              void* d_out, int out_size, void* d_ws, size_t ws_size,
                              hipStream_t stream) {
    const int* nodes  = (const int*)d_in[0];
    const int* uids   = (const int*)d_in[1];
    const int* layer  = (const int*)d_in[3];
    const int* col    = (const int*)d_in[4];
    const float* agg    = (const float*)d_in[5];
    const float* ff     = (const float*)d_in[6];
    const float* Wv_agg = (const float*)d_in[7];
    const float* Wv_ff  = (const float*)d_in[8];
    const float* Wk     = (const float*)d_in[9];
    const float* Wq     = (const float*)d_in[10];
    const float* mu     = (const float*)d_in[11];

    // ws layout: WT bf16 (4*128*128 = 256 KB), then f32 intermediates
    u16*   WT      = (u16*)d_ws;
    float* embed_v = (float*)((char*)d_ws + 4 * ND * ND * sizeof(u16));
    float* selfA   = embed_v + (size_t)NU * ND;
    float* selfF   = selfA + (size_t)NB * ND;
    float* K0      = selfF + (size_t)NB * ND;
    float* K1      = K0 + (size_t)NB * ND;
    float* Q0      = K1 + (size_t)NB * ND;
    float* Q1      = Q0 + (size_t)NB * ND;

    float* out = (float*)d_out;

    prep_wt<<<32, 256, 0, stream>>>(Wv_agg, Wk, Wq, Wv_ff, WT);

    gemm_all<<<EMBED_BLOCKS + 6 * (NB / 128), 256, 0, stream>>>(
        agg, ff, WT, uids, nodes,
        embed_v, selfA, selfF, K0, K1, Q0, Q1);

    finalize<<<NB, 128, 0, stream>>>(
        layer, col, embed_v, selfA, selfF, K0, K1, Q0, Q1, mu, out);
}